// Round 5
// baseline (317.654 us; speedup 1.0000x reference)
//
#include <hip/hip_runtime.h>
#include <hip/hip_fp16.h>
#include <math.h>
#include <stdint.h>

// VQ via f16x3 split MFMA (32x32x16): dot = (hi.hi + hi.lo + lo.hi) * 2^-20.
// diff = (v2 - 2*dot) + c2 fp32-rounded per np; argmin codes 1..4095, ties -> lowest n.
// V hi/lo planes pre-split into d_out (gather overwrites it at the end).

#define M_TOTAL 16384
#define NCODES  4096
#define D_DIM   256

#define OUT_OFF_IDX  (M_TOTAL * D_DIM)
#define OUT_OFF_LOSS (OUT_OFF_IDX + M_TOTAL)

#define NPART 16          // n-dim grid splits (4096 / 256)
#define WPLANE (NCODES * D_DIM)
#define VPLANE (M_TOTAL * D_DIM)

typedef _Float16 half8 __attribute__((ext_vector_type(8)));
typedef _Float16 half4v __attribute__((ext_vector_type(4)));
typedef float    float16v __attribute__((ext_vector_type(16)));

// ---- fused split + row sum-of-squares (numpy pairwise chain order) ----
// block = 128 threads = 2 waves; each wave owns 64 rows; k-tiles of 64 cols.
__global__ __launch_bounds__(128) void prep_kernel(
    const float* __restrict__ X, _Float16* __restrict__ hi, _Float16* __restrict__ lo,
    float* __restrict__ sq)
{
  __shared__ float T[2][64 * 66];
  const int w = threadIdx.x >> 6, l = threadIdx.x & 63;
  const int r0 = blockIdx.x * 128 + w * 64;
  float* Tw = T[w];
  float rj[8];
  float s0 = 0.0f, s1 = 0.0f;
#pragma unroll
  for (int kt = 0; kt < 4; ++kt) {
    __syncthreads();
#pragma unroll
    for (int s = 0; s < 16; ++s) {      // stage 64 rows x 64 cols, coalesced f4
      const int row = s * 4 + (l >> 4), c4 = l & 15;
      const size_t go = (size_t)(r0 + row) * D_DIM + kt * 64 + c4 * 4;
      float4 v = *(const float4*)(X + go);
      float xs[4] = {v.x, v.y, v.z, v.w};
      union { half4v h; _Float16 e[4]; } uh, ul;
#pragma unroll
      for (int j = 0; j < 4; ++j) {
        float sc = xs[j] * 1024.0f;          // exact pow2 scale
        _Float16 h = (_Float16)sc;           // RN
        uh.e[j] = h;
        ul.e[j] = (_Float16)(sc - (float)h); // RN of exact residual
      }
      *(half4v*)(hi + go) = uh.h;
      *(half4v*)(lo + go) = ul.h;
      *(float4*)&Tw[row * 66 + c4 * 4] = v;
    }
    __syncthreads();
#pragma unroll
    for (int c4 = 0; c4 < 16; ++c4) {   // thread l consumes row l, np chain order
      float4 v = *(const float4*)&Tw[l * 66 + c4 * 4];
      float e[4] = {v.x, v.y, v.z, v.w};
#pragma unroll
      for (int t = 0; t < 4; ++t) {
        const int k = kt * 64 + c4 * 4 + t;
        const int j = k & 7;
        float sqv = __fmul_rn(e[t], e[t]);
        if ((k & 127) < 8) rj[j] = sqv;
        else rj[j] = __fadd_rn(rj[j], sqv);
      }
    }
    if (kt == 1) s0 = __fadd_rn(__fadd_rn(__fadd_rn(rj[0], rj[1]), __fadd_rn(rj[2], rj[3])),
                                __fadd_rn(__fadd_rn(rj[4], rj[5]), __fadd_rn(rj[6], rj[7])));
    if (kt == 3) s1 = __fadd_rn(__fadd_rn(__fadd_rn(rj[0], rj[1]), __fadd_rn(rj[2], rj[3])),
                                __fadd_rn(__fadd_rn(rj[4], rj[5]), __fadd_rn(rj[6], rj[7])));
  }
  sq[r0 + l] = __fadd_rn(s0, s1);
}

// ---- main: 32x32x16 MFMA f16x3 GEMM + argmin ----
// block 128m x 256n, 4 waves 2x2; wave tile 64m x 128n = 2 mb x 4 nb of 32x32.
// A planes in LDS (register-prefetch staged, XOR chunk swizzle); B from global/L2.
__global__ __launch_bounds__(256, 2) void vq_mfma_kernel(
    const _Float16* __restrict__ Vhi, const _Float16* __restrict__ Vlo,
    const _Float16* __restrict__ Whi,
    const float* __restrict__ v2, const float* __restrict__ c2,
    uint64_t* __restrict__ pk)
{
  __shared__ __align__(16) _Float16 lds[16384];   // [plane(2)][8192]; m*64 + c*8, c = kb^(m&7)

  const int tid  = threadIdx.x;
  const int lane = tid & 63;
  const int wave = tid >> 6;
  const int wr = wave >> 1, wc = wave & 1;
  const int l31 = lane & 31, lhi = lane >> 5;
  const int m0 = blockIdx.x * 128;
  const int n0 = blockIdx.y * 256;

  // staging map: q = tid + 256u -> m = q>>3, kb = q&7, c = kb^(m&7)
  int src[4], dst8[4];
#pragma unroll
  for (int u = 0; u < 4; ++u) {
    const int q = tid + 256 * u, m = q >> 3, kb = q & 7;
    src[u]  = (m0 + m) * D_DIM + kb * 8;
    dst8[u] = m * 64 + (kb ^ (m & 7)) * 8;
  }

  float16v acc[2][4];
#pragma unroll
  for (int mb = 0; mb < 2; ++mb)
#pragma unroll
    for (int nb = 0; nb < 4; ++nb) acc[mb][nb] = (float16v)0.0f;

  half8 sh[4], sl[4];
#pragma unroll
  for (int u = 0; u < 4; ++u) {
    sh[u] = *(const half8*)(Vhi + src[u]);
    sl[u] = *(const half8*)(Vlo + src[u]);
  }

  for (int kt = 0; kt < 4; ++kt) {
    if (kt) __syncthreads();            // all waves done reading previous tile
#pragma unroll
    for (int u = 0; u < 4; ++u) {
      *(half8*)(lds + dst8[u])        = sh[u];
      *(half8*)(lds + 8192 + dst8[u]) = sl[u];
    }
    __syncthreads();
    if (kt < 3) {                       // prefetch next tile into regs (consumed by ds_write next kt)
#pragma unroll
      for (int u = 0; u < 4; ++u) {
        sh[u] = *(const half8*)(Vhi + src[u] + (kt + 1) * 64);
        sl[u] = *(const half8*)(Vlo + src[u] + (kt + 1) * 64);
      }
    }
#pragma unroll
    for (int ks = 0; ks < 4; ++ks) {    // k-steps of 16
      half8 ah[2], al[2];
#pragma unroll
      for (int mb = 0; mb < 2; ++mb) {
        const int m = wr * 64 + mb * 32 + l31;
        const int c = (ks * 2 + lhi) ^ (m & 7);
        ah[mb] = *(const half8*)(lds + m * 64 + c * 8);
        al[mb] = *(const half8*)(lds + 8192 + m * 64 + c * 8);
      }
      half8 bh[4], bl[4];
#pragma unroll
      for (int nb = 0; nb < 4; ++nb) {
        const _Float16* bp = Whi + (size_t)(n0 + wc * 128 + nb * 32 + l31) * D_DIM
                             + kt * 64 + ks * 16 + lhi * 8;
        bh[nb] = *(const half8*)bp;
        bl[nb] = *(const half8*)(bp + WPLANE);
      }
      // product-major: same-acc dependency distance = 8 MFMAs
#pragma unroll
      for (int nb = 0; nb < 4; ++nb)
#pragma unroll
        for (int mb = 0; mb < 2; ++mb)
          acc[mb][nb] = __builtin_amdgcn_mfma_f32_32x32x16_f16(ah[mb], bh[nb], acc[mb][nb], 0, 0, 0);
#pragma unroll
      for (int nb = 0; nb < 4; ++nb)
#pragma unroll
        for (int mb = 0; mb < 2; ++mb)
          acc[mb][nb] = __builtin_amdgcn_mfma_f32_32x32x16_f16(ah[mb], bl[nb], acc[mb][nb], 0, 0, 0);
#pragma unroll
      for (int nb = 0; nb < 4; ++nb)
#pragma unroll
        for (int mb = 0; mb < 2; ++mb)
          acc[mb][nb] = __builtin_amdgcn_mfma_f32_32x32x16_f16(al[mb], bh[nb], acc[mb][nb], 0, 0, 0);
    }
  }

  // ---- epilogue: diff = (v2 - 2*dot) + c2 (np order), argmin, tie -> lowest n ----
  float c2r[4];
#pragma unroll
  for (int nb = 0; nb < 4; ++nb) c2r[nb] = c2[n0 + wc * 128 + nb * 32 + l31];

  __syncthreads();                      // done reading A; reuse LDS as red[128][2]
  uint64_t* red = (uint64_t*)lds;

#pragma unroll
  for (int mb = 0; mb < 2; ++mb) {
#pragma unroll
    for (int r = 0; r < 16; ++r) {
      const int mloc = wr * 64 + mb * 32 + (r & 3) + 8 * (r >> 2) + 4 * lhi;
      const float v2m = v2[m0 + mloc];  // uniform per half-wave
      uint64_t b = ~0ULL;
#pragma unroll
      for (int nb = 0; nb < 4; ++nb) {
        const int n = n0 + wc * 128 + nb * 32 + l31;
        float dot = acc[mb][nb][r] * 0x1p-20f;            // exact pow2 unscale
        float dd  = __fadd_rn(__fsub_rn(v2m, 2.0f * dot), c2r[nb]);
        if (n == 0) dd = INFINITY;                        // exclude code 0
        uint64_t p = ((uint64_t)__float_as_uint(dd) << 32) | (uint32_t)n;
        if (p < b) b = p;                                 // dd>0 -> bits monotonic
      }
#pragma unroll
      for (int off = 16; off; off >>= 1) {                // reduce within 32-lane half
        uint64_t o = __shfl_xor((unsigned long long)b, off);
        if (o < b) b = o;
      }
      if (l31 == 0) red[mloc * 2 + wc] = b;
    }
  }
  __syncthreads();
  if (tid < 128) {
    uint64_t a0 = red[tid * 2], a1 = red[tid * 2 + 1];
    pk[blockIdx.y * M_TOTAL + m0 + tid] = a0 < a1 ? a0 : a1;
  }
}

// ---- gather: one wave per query, no barriers ----
__global__ __launch_bounds__(256) void gather_kernel(
    const float* __restrict__ V, const float* __restrict__ W,
    const uint64_t* __restrict__ pk,
    float* __restrict__ out, float* __restrict__ outIdx,
    float* __restrict__ lossPartial)
{
  const int q = blockIdx.x * 4 + (threadIdx.x >> 6);
  const int l = threadIdx.x & 63;
  uint64_t b = (l < NPART) ? pk[(size_t)l * M_TOTAL + q] : ~0ULL;
#pragma unroll
  for (int off = 32; off; off >>= 1) {
    uint64_t o = __shfl_xor((unsigned long long)b, off);
    if (o < b) b = o;
  }
  float4 vv = *(const float4*)(V + (size_t)q * D_DIM + l * 4);
  const float inv = 0.00390625f;
  bool ne = (vv.x != inv) | (vv.y != inv) | (vv.z != inv) | (vv.w != inv);
  const int idx = __ballot(ne) ? (int)(uint32_t)b : 0;
  float4 o4 = *(const float4*)(W + (size_t)idx * D_DIM + l * 4);
  *(float4*)(out + (size_t)q * D_DIM + l * 4) = o4;
  if (l == 0) outIdx[q] = (float)idx;
  float dx = o4.x - vv.x, dy = o4.y - vv.y, dz = o4.z - vv.z, dw = o4.w - vv.w;
  float s = dx * dx + dy * dy + dz * dz + dw * dw;
#pragma unroll
  for (int off = 32; off; off >>= 1) s += __shfl_xor(s, off);
  if (l == 0) lossPartial[q] = s;
}

__global__ __launch_bounds__(256) void finalize_kernel(
    const float* __restrict__ lossPartial, float* __restrict__ out)
{
  const int t = threadIdx.x;
  __shared__ float red[256];
  float s = 0.0f;
  for (int i = t; i < M_TOTAL; i += 256) s += lossPartial[i];
  red[t] = s;
  __syncthreads();
  for (int st = 128; st > 0; st >>= 1) {
    if (t < st) red[t] += red[t + st];
    __syncthreads();
  }
  if (t == 0) {
    out[0] = (float)((double)red[0] / (double)(M_TOTAL * D_DIM));  // loss
    out[1] = 0.0f;                                                 // used
  }
}

extern "C" void kernel_launch(void* const* d_in, const int* in_sizes, int n_in,
                              void* d_out, int out_size, void* d_ws, size_t ws_size,
                              hipStream_t stream) {
  const float* V = (const float*)d_in[0];   // 16384 x 256
  const float* W = (const float*)d_in[1];   // 4096 x 256
  float* out = (float*)d_out;

  // V planes live in d_out (16384*256*4 bytes); gather overwrites later.
  _Float16* Vhi = (_Float16*)d_out;
  _Float16* Vlo = Vhi + VPLANE;

  char* ws = (char*)d_ws;
  _Float16* Whi = (_Float16*)(ws);                        // 2 MB
  _Float16* Wlo = (_Float16*)(ws + 2097152);              // 2 MB (= Whi + WPLANE)
  float*    c2  = (float*)(ws + 4194304);                 // 16 KB
  float*    v2  = (float*)(ws + 4194304 + 16384);         // 64 KB
  uint64_t* pk  = (uint64_t*)(ws + 4194304 + 16384 + 65536);   // 16*16384*8 = 2 MB
  float* lossPartial = (float*)(ws + 4194304 + 16384 + 65536 + 2097152);

  prep_kernel<<<NCODES / 128, 128, 0, stream>>>(W, Whi, Wlo, c2);
  prep_kernel<<<M_TOTAL / 128, 128, 0, stream>>>(V, Vhi, Vlo, v2);
  vq_mfma_kernel<<<dim3(M_TOTAL / 128, NCODES / 256), 256, 0, stream>>>(Vhi, Vlo, Whi, v2, c2, pk);
  gather_kernel<<<M_TOTAL / 4, 256, 0, stream>>>(V, W, pk, out, out + OUT_OFF_IDX, lossPartial);
  finalize_kernel<<<1, 256, 0, stream>>>(lossPartial, out + OUT_OFF_LOSS);
}

// Round 6
// 236.588 us; speedup vs baseline: 1.3426x; 1.3426x over previous
//
#include <hip/hip_runtime.h>
#include <hip/hip_fp16.h>
#include <math.h>
#include <stdint.h>

// VQ via f16x3 split MFMA (32x32x16): dot = (hi.hi + hi.lo + lo.hi) * 2^-20.
// diff = (v2 - 2*dot) + c2 fp32-rounded per np; argmin codes 1..4095, ties -> lowest n.
// V hi/lo planes pre-split into d_out (gather overwrites at the end).
// W packed into MFMA-fragment order: Bp[panel][kstep][plane][lane][8] -> 1KB coalesced frags.

#define M_TOTAL 16384
#define NCODES  4096
#define D_DIM   256

#define OUT_OFF_IDX  (M_TOTAL * D_DIM)
#define OUT_OFF_LOSS (OUT_OFF_IDX + M_TOTAL)

#define NPART 16          // n-dim grid splits (4096 / 256)
#define VPLANE (M_TOTAL * D_DIM)

typedef _Float16 half8 __attribute__((ext_vector_type(8)));
typedef _Float16 half4v __attribute__((ext_vector_type(4)));
typedef float    float16v __attribute__((ext_vector_type(16)));

// ---- V prep: split to row-major hi/lo planes + row sumsq (np pairwise chain) ----
// 1 wave per block, 64 rows; LDS transpose for coalesced loads.
__global__ __launch_bounds__(64) void prep_v_kernel(
    const float* __restrict__ X, _Float16* __restrict__ hi, _Float16* __restrict__ lo,
    float* __restrict__ sq)
{
  __shared__ float T[64 * 66];
  const int l = threadIdx.x;
  const int r0 = blockIdx.x * 64;
  float rj[8];
  float s0 = 0.0f, s1 = 0.0f;
#pragma unroll
  for (int kt = 0; kt < 4; ++kt) {
    __syncthreads();
#pragma unroll
    for (int s = 0; s < 16; ++s) {      // stage 64 rows x 64 cols, coalesced f4
      const int row = s * 4 + (l >> 4), c4 = l & 15;
      const size_t go = (size_t)(r0 + row) * D_DIM + kt * 64 + c4 * 4;
      float4 v = *(const float4*)(X + go);
      float xs[4] = {v.x, v.y, v.z, v.w};
      union { half4v h; _Float16 e[4]; } uh, ul;
#pragma unroll
      for (int j = 0; j < 4; ++j) {
        float sc = xs[j] * 1024.0f;          // exact pow2 scale
        _Float16 h = (_Float16)sc;           // RN
        uh.e[j] = h;
        ul.e[j] = (_Float16)(sc - (float)h); // RN of exact residual
      }
      *(half4v*)(hi + go) = uh.h;
      *(half4v*)(lo + go) = ul.h;
      *(float4*)&T[row * 66 + c4 * 4] = v;
    }
    __syncthreads();
#pragma unroll
    for (int c4 = 0; c4 < 16; ++c4) {   // thread l consumes row l, np chain order
      float4 v = *(const float4*)&T[l * 66 + c4 * 4];
      float e[4] = {v.x, v.y, v.z, v.w};
#pragma unroll
      for (int t = 0; t < 4; ++t) {
        const int k = kt * 64 + c4 * 4 + t;
        const int j = k & 7;
        float sqv = __fmul_rn(e[t], e[t]);
        if ((k & 127) < 8) rj[j] = sqv;
        else rj[j] = __fadd_rn(rj[j], sqv);
      }
    }
    if (kt == 1) s0 = __fadd_rn(__fadd_rn(__fadd_rn(rj[0], rj[1]), __fadd_rn(rj[2], rj[3])),
                                __fadd_rn(__fadd_rn(rj[4], rj[5]), __fadd_rn(rj[6], rj[7])));
    if (kt == 3) s1 = __fadd_rn(__fadd_rn(__fadd_rn(rj[0], rj[1]), __fadd_rn(rj[2], rj[3])),
                                __fadd_rn(__fadd_rn(rj[4], rj[5]), __fadd_rn(rj[6], rj[7])));
  }
  sq[r0 + l] = __fadd_rn(s0, s1);
}

// ---- W prep: split + pack into fragment order + c2 chain ----
// Bp element (n,k,plane): panel=n>>5, kstep=k>>4, lhi=(k>>3)&1, j=k&7
// offset = ((panel*16+kstep)*2+plane)*1024 + lhi*256 + (n&31)*8 + j
__global__ __launch_bounds__(64) void prep_w_kernel(
    const float* __restrict__ W, _Float16* __restrict__ Bp, float* __restrict__ c2)
{
  __shared__ float T[64 * 66];
  const int l = threadIdx.x;
  const int r0 = blockIdx.x * 64;
  const int panel = (r0 >> 5) + (l >> 5);
  const int nin = l & 31;
  float rj[8];
  float s0 = 0.0f, s1 = 0.0f;
#pragma unroll
  for (int kt = 0; kt < 4; ++kt) {
    __syncthreads();
#pragma unroll
    for (int s = 0; s < 16; ++s) {
      const int row = s * 4 + (l >> 4), c4 = l & 15;
      *(float4*)&T[row * 66 + c4 * 4] =
          *(const float4*)(W + (size_t)(r0 + row) * D_DIM + kt * 64 + c4 * 4);
    }
    __syncthreads();
    union { half8 v; _Float16 e[8]; } uh, ul;
#pragma unroll
    for (int c4 = 0; c4 < 16; ++c4) {   // thread l owns row r0+l
      float4 v = *(const float4*)&T[l * 66 + c4 * 4];
      float e[4] = {v.x, v.y, v.z, v.w};
#pragma unroll
      for (int t = 0; t < 4; ++t) {
        const int k = kt * 64 + c4 * 4 + t;
        float sc = e[t] * 1024.0f;           // exact pow2 scale
        _Float16 h = (_Float16)sc;           // RN
        uh.e[(c4 & 1) * 4 + t] = h;
        ul.e[(c4 & 1) * 4 + t] = (_Float16)(sc - (float)h);
        const int j = k & 7;
        float sqv = __fmul_rn(e[t], e[t]);
        if ((k & 127) < 8) rj[j] = sqv;
        else rj[j] = __fadd_rn(rj[j], sqv);
      }
      if (c4 & 1) {
        const int g = kt * 8 + (c4 >> 1);    // 8-half group 0..31
        const int kstep = g >> 1, lhi = g & 1;
        _Float16* dst = Bp + ((size_t)panel * 16 + kstep) * 2048 + lhi * 256 + nin * 8;
        *(half8*)dst = uh.v;                 // hi plane
        *(half8*)(dst + 1024) = ul.v;        // lo plane
      }
    }
    if (kt == 1) s0 = __fadd_rn(__fadd_rn(__fadd_rn(rj[0], rj[1]), __fadd_rn(rj[2], rj[3])),
                                __fadd_rn(__fadd_rn(rj[4], rj[5]), __fadd_rn(rj[6], rj[7])));
    if (kt == 3) s1 = __fadd_rn(__fadd_rn(__fadd_rn(rj[0], rj[1]), __fadd_rn(rj[2], rj[3])),
                                __fadd_rn(__fadd_rn(rj[4], rj[5]), __fadd_rn(rj[6], rj[7])));
  }
  c2[r0 + l] = __fadd_rn(s0, s1);
}

// ---- main: 32x32x16 MFMA f16x3 GEMM + argmin ----
// block 128m x 256n, 4 waves 2x2; wave tile 64m x 128n = 2 mb x 4 nb.
// A planes in LDS (reg-prefetch staged, XOR swizzle); B coalesced packed frags from L2.
__global__ __launch_bounds__(256, 2) void vq_mfma_kernel(
    const _Float16* __restrict__ Vhi, const _Float16* __restrict__ Vlo,
    const _Float16* __restrict__ Bp,
    const float* __restrict__ v2, const float* __restrict__ c2,
    uint64_t* __restrict__ pk)
{
  __shared__ __align__(16) _Float16 lds[16384];   // [plane(2)][8192]; m*64 + c*8, c = kb^(m&7)

  const int tid  = threadIdx.x;
  const int lane = tid & 63;
  const int wave = tid >> 6;
  const int wr = wave >> 1, wc = wave & 1;
  const int l31 = lane & 31, lhi = lane >> 5;
  const int m0 = blockIdx.x * 128;
  const int n0 = blockIdx.y * 256;
  const int panelBase = (n0 >> 5) + wc * 4;

  // staging map: q = tid + 256u -> m = q>>3, kb = q&7, c = kb^(m&7)
  int src[4], dst8[4];
#pragma unroll
  for (int u = 0; u < 4; ++u) {
    const int q = tid + 256 * u, m = q >> 3, kb = q & 7;
    src[u]  = (m0 + m) * D_DIM + kb * 8;
    dst8[u] = m * 64 + (kb ^ (m & 7)) * 8;
  }

  float16v acc[2][4];
#pragma unroll
  for (int mb = 0; mb < 2; ++mb)
#pragma unroll
    for (int nb = 0; nb < 4; ++nb) acc[mb][nb] = (float16v)0.0f;

  half8 sh[4], sl[4];
#pragma unroll
  for (int u = 0; u < 4; ++u) {
    sh[u] = *(const half8*)(Vhi + src[u]);
    sl[u] = *(const half8*)(Vlo + src[u]);
  }

  for (int kt = 0; kt < 4; ++kt) {
    if (kt) __syncthreads();            // all waves done reading previous tile
#pragma unroll
    for (int u = 0; u < 4; ++u) {
      *(half8*)(lds + dst8[u])        = sh[u];
      *(half8*)(lds + 8192 + dst8[u]) = sl[u];
    }
    __syncthreads();
    if (kt < 3) {                       // prefetch next A tile into regs
#pragma unroll
      for (int u = 0; u < 4; ++u) {
        sh[u] = *(const half8*)(Vhi + src[u] + (kt + 1) * 64);
        sl[u] = *(const half8*)(Vlo + src[u] + (kt + 1) * 64);
      }
    }
#pragma unroll
    for (int ks = 0; ks < 4; ++ks) {    // k-steps of 16
      const int kstep = kt * 4 + ks;
      half8 ah[2], al[2];
#pragma unroll
      for (int mb = 0; mb < 2; ++mb) {
        const int m = wr * 64 + mb * 32 + l31;
        const int c = (ks * 2 + lhi) ^ (m & 7);
        ah[mb] = *(const half8*)(lds + m * 64 + c * 8);
        al[mb] = *(const half8*)(lds + 8192 + m * 64 + c * 8);
      }
      half8 bh[4], bl[4];
#pragma unroll
      for (int nb = 0; nb < 4; ++nb) {  // 1KB fully-coalesced fragment loads
        const _Float16* bp = Bp + ((size_t)(panelBase + nb) * 16 + kstep) * 2048 + lane * 8;
        bh[nb] = *(const half8*)bp;
        bl[nb] = *(const half8*)(bp + 1024);
      }
      // product-major: same-acc dependency distance = 8 MFMAs
#pragma unroll
      for (int nb = 0; nb < 4; ++nb)
#pragma unroll
        for (int mb = 0; mb < 2; ++mb)
          acc[mb][nb] = __builtin_amdgcn_mfma_f32_32x32x16_f16(ah[mb], bh[nb], acc[mb][nb], 0, 0, 0);
#pragma unroll
      for (int nb = 0; nb < 4; ++nb)
#pragma unroll
        for (int mb = 0; mb < 2; ++mb)
          acc[mb][nb] = __builtin_amdgcn_mfma_f32_32x32x16_f16(ah[mb], bl[nb], acc[mb][nb], 0, 0, 0);
#pragma unroll
      for (int nb = 0; nb < 4; ++nb)
#pragma unroll
        for (int mb = 0; mb < 2; ++mb)
          acc[mb][nb] = __builtin_amdgcn_mfma_f32_32x32x16_f16(al[mb], bh[nb], acc[mb][nb], 0, 0, 0);
    }
  }

  // ---- epilogue: diff = (v2 - 2*dot) + c2 (np order), argmin, tie -> lowest n ----
  float c2r[4];
#pragma unroll
  for (int nb = 0; nb < 4; ++nb) c2r[nb] = c2[n0 + wc * 128 + nb * 32 + l31];

  __syncthreads();                      // done reading A; reuse LDS as red[128][2]
  uint64_t* red = (uint64_t*)lds;

#pragma unroll
  for (int mb = 0; mb < 2; ++mb) {
#pragma unroll
    for (int r = 0; r < 16; ++r) {
      const int mloc = wr * 64 + mb * 32 + (r & 3) + 8 * (r >> 2) + 4 * lhi;
      const float v2m = v2[m0 + mloc];  // uniform per half-wave
      uint64_t b = ~0ULL;
#pragma unroll
      for (int nb = 0; nb < 4; ++nb) {
        const int n = n0 + wc * 128 + nb * 32 + l31;
        float dot = acc[mb][nb][r] * 0x1p-20f;            // exact pow2 unscale
        float dd  = __fadd_rn(__fsub_rn(v2m, 2.0f * dot), c2r[nb]);
        if (n == 0) dd = INFINITY;                        // exclude code 0
        uint64_t p = ((uint64_t)__float_as_uint(dd) << 32) | (uint32_t)n;
        if (p < b) b = p;                                 // dd>0 -> bits monotonic
      }
#pragma unroll
      for (int off = 16; off; off >>= 1) {                // reduce within 32-lane half
        uint64_t o = __shfl_xor((unsigned long long)b, off);
        if (o < b) b = o;
      }
      if (l31 == 0) red[mloc * 2 + wc] = b;
    }
  }
  __syncthreads();
  if (tid < 128) {
    uint64_t a0 = red[tid * 2], a1 = red[tid * 2 + 1];
    pk[blockIdx.y * M_TOTAL + m0 + tid] = a0 < a1 ? a0 : a1;
  }
}

// ---- gather: one wave per query, no barriers ----
__global__ __launch_bounds__(256) void gather_kernel(
    const float* __restrict__ V, const float* __restrict__ W,
    const uint64_t* __restrict__ pk,
    float* __restrict__ out, float* __restrict__ outIdx,
    float* __restrict__ lossPartial)
{
  const int q = blockIdx.x * 4 + (threadIdx.x >> 6);
  const int l = threadIdx.x & 63;
  uint64_t b = (l < NPART) ? pk[(size_t)l * M_TOTAL + q] : ~0ULL;
#pragma unroll
  for (int off = 32; off; off >>= 1) {
    uint64_t o = __shfl_xor((unsigned long long)b, off);
    if (o < b) b = o;
  }
  float4 vv = *(const float4*)(V + (size_t)q * D_DIM + l * 4);
  const float inv = 0.00390625f;
  bool ne = (vv.x != inv) | (vv.y != inv) | (vv.z != inv) | (vv.w != inv);
  const int idx = __ballot(ne) ? (int)(uint32_t)b : 0;
  float4 o4 = *(const float4*)(W + (size_t)idx * D_DIM + l * 4);
  *(float4*)(out + (size_t)q * D_DIM + l * 4) = o4;
  if (l == 0) outIdx[q] = (float)idx;
  float dx = o4.x - vv.x, dy = o4.y - vv.y, dz = o4.z - vv.z, dw = o4.w - vv.w;
  float s = dx * dx + dy * dy + dz * dz + dw * dw;
#pragma unroll
  for (int off = 32; off; off >>= 1) s += __shfl_xor(s, off);
  if (l == 0) lossPartial[q] = s;
}

__global__ __launch_bounds__(256) void finalize_kernel(
    const float* __restrict__ lossPartial, float* __restrict__ out)
{
  const int t = threadIdx.x;
  __shared__ float red[256];
  float s = 0.0f;
  for (int i = t; i < M_TOTAL; i += 256) s += lossPartial[i];
  red[t] = s;
  __syncthreads();
  for (int st = 128; st > 0; st >>= 1) {
    if (t < st) red[t] += red[t + st];
    __syncthreads();
  }
  if (t == 0) {
    out[0] = (float)((double)red[0] / (double)(M_TOTAL * D_DIM));  // loss
    out[1] = 0.0f;                                                 // used
  }
}

extern "C" void kernel_launch(void* const* d_in, const int* in_sizes, int n_in,
                              void* d_out, int out_size, void* d_ws, size_t ws_size,
                              hipStream_t stream) {
  const float* V = (const float*)d_in[0];   // 16384 x 256
  const float* W = (const float*)d_in[1];   // 4096 x 256
  float* out = (float*)d_out;

  // V planes live in d_out (16384*256*4 bytes); gather overwrites later.
  _Float16* Vhi = (_Float16*)d_out;
  _Float16* Vlo = Vhi + VPLANE;

  char* ws = (char*)d_ws;
  _Float16* Bp  = (_Float16*)(ws);                        // packed W frags: 8 MB
  float*    c2  = (float*)(ws + 8388608);                 // 16 KB
  float*    v2  = (float*)(ws + 8388608 + 16384);         // 64 KB
  uint64_t* pk  = (uint64_t*)(ws + 8388608 + 16384 + 65536);   // 16*16384*8 = 2 MB
  float* lossPartial = (float*)(ws + 8388608 + 16384 + 65536 + 2097152);  // 64 KB

  prep_w_kernel<<<NCODES / 64, 64, 0, stream>>>(W, Bp, c2);
  prep_v_kernel<<<M_TOTAL / 64, 64, 0, stream>>>(V, Vhi, Vlo, v2);
  vq_mfma_kernel<<<dim3(M_TOTAL / 128, NCODES / 256), 256, 0, stream>>>(Vhi, Vlo, Bp, v2, c2, pk);
  gather_kernel<<<M_TOTAL / 4, 256, 0, stream>>>(V, W, pk, out, out + OUT_OFF_IDX, lossPartial);
  finalize_kernel<<<1, 256, 0, stream>>>(lossPartial, out + OUT_OFF_LOSS);
}

// Round 7
// 223.441 us; speedup vs baseline: 1.4216x; 1.0588x over previous
//
#include <hip/hip_runtime.h>
#include <hip/hip_fp16.h>
#include <math.h>
#include <stdint.h>

// VQ via f16x3 split MFMA (32x32x16): dot = (hi.hi + hi.lo + lo.hi) * 2^-20.
// diff = (v2 - 2*dot) + c2 fp32-rounded per np; argmin codes 1..4095, ties -> lowest n.
// R7: wave tile 128x128 (acc 256 VGPR, 1 wave/SIMD) -> B feed demand 85 B/cyc (was 171),
// XCD-swizzled panels keep B L2-resident; register ping-pong B prefetch across barriers.

#define M_TOTAL 16384
#define NCODES  4096
#define D_DIM   256

#define OUT_OFF_IDX  (M_TOTAL * D_DIM)
#define OUT_OFF_LOSS (OUT_OFF_IDX + M_TOTAL)

#define NPART 16
#define VPLANE (M_TOTAL * D_DIM)

typedef _Float16 half8 __attribute__((ext_vector_type(8)));
typedef _Float16 half4v __attribute__((ext_vector_type(4)));
typedef float    float16v __attribute__((ext_vector_type(16)));

// ---- V prep: split to row-major hi/lo planes + row sumsq (np pairwise chain) ----
__global__ __launch_bounds__(64) void prep_v_kernel(
    const float* __restrict__ X, _Float16* __restrict__ hi, _Float16* __restrict__ lo,
    float* __restrict__ sq)
{
  __shared__ float T[64 * 66];
  const int l = threadIdx.x;
  const int r0 = blockIdx.x * 64;
  float rj[8];
  float s0 = 0.0f, s1 = 0.0f;
#pragma unroll
  for (int kt = 0; kt < 4; ++kt) {
    __syncthreads();
#pragma unroll
    for (int s = 0; s < 16; ++s) {
      const int row = s * 4 + (l >> 4), c4 = l & 15;
      const size_t go = (size_t)(r0 + row) * D_DIM + kt * 64 + c4 * 4;
      float4 v = *(const float4*)(X + go);
      float xs[4] = {v.x, v.y, v.z, v.w};
      union { half4v h; _Float16 e[4]; } uh, ul;
#pragma unroll
      for (int j = 0; j < 4; ++j) {
        float sc = xs[j] * 1024.0f;          // exact pow2 scale
        _Float16 h = (_Float16)sc;           // RN
        uh.e[j] = h;
        ul.e[j] = (_Float16)(sc - (float)h); // RN of exact residual
      }
      *(half4v*)(hi + go) = uh.h;
      *(half4v*)(lo + go) = ul.h;
      *(float4*)&T[row * 66 + c4 * 4] = v;
    }
    __syncthreads();
#pragma unroll
    for (int c4 = 0; c4 < 16; ++c4) {
      float4 v = *(const float4*)&T[l * 66 + c4 * 4];
      float e[4] = {v.x, v.y, v.z, v.w};
#pragma unroll
      for (int t = 0; t < 4; ++t) {
        const int k = kt * 64 + c4 * 4 + t;
        const int j = k & 7;
        float sqv = __fmul_rn(e[t], e[t]);
        if ((k & 127) < 8) rj[j] = sqv;
        else rj[j] = __fadd_rn(rj[j], sqv);
      }
    }
    if (kt == 1) s0 = __fadd_rn(__fadd_rn(__fadd_rn(rj[0], rj[1]), __fadd_rn(rj[2], rj[3])),
                                __fadd_rn(__fadd_rn(rj[4], rj[5]), __fadd_rn(rj[6], rj[7])));
    if (kt == 3) s1 = __fadd_rn(__fadd_rn(__fadd_rn(rj[0], rj[1]), __fadd_rn(rj[2], rj[3])),
                                __fadd_rn(__fadd_rn(rj[4], rj[5]), __fadd_rn(rj[6], rj[7])));
  }
  sq[r0 + l] = __fadd_rn(s0, s1);
}

// ---- W prep: split + pack into fragment order + c2 chain ----
// Bp element (n,k,plane): panel=n>>5, kstep=k>>4, lhi=(k>>3)&1, j=k&7
// offset = ((panel*16+kstep)*2+plane)*1024 + lhi*256 + (n&31)*8 + j
__global__ __launch_bounds__(64) void prep_w_kernel(
    const float* __restrict__ W, _Float16* __restrict__ Bp, float* __restrict__ c2)
{
  __shared__ float T[64 * 66];
  const int l = threadIdx.x;
  const int r0 = blockIdx.x * 64;
  const int panel = (r0 >> 5) + (l >> 5);
  const int nin = l & 31;
  float rj[8];
  float s0 = 0.0f, s1 = 0.0f;
#pragma unroll
  for (int kt = 0; kt < 4; ++kt) {
    __syncthreads();
#pragma unroll
    for (int s = 0; s < 16; ++s) {
      const int row = s * 4 + (l >> 4), c4 = l & 15;
      *(float4*)&T[row * 66 + c4 * 4] =
          *(const float4*)(W + (size_t)(r0 + row) * D_DIM + kt * 64 + c4 * 4);
    }
    __syncthreads();
    union { half8 v; _Float16 e[8]; } uh, ul;
#pragma unroll
    for (int c4 = 0; c4 < 16; ++c4) {
      float4 v = *(const float4*)&T[l * 66 + c4 * 4];
      float e[4] = {v.x, v.y, v.z, v.w};
#pragma unroll
      for (int t = 0; t < 4; ++t) {
        const int k = kt * 64 + c4 * 4 + t;
        float sc = e[t] * 1024.0f;
        _Float16 h = (_Float16)sc;
        uh.e[(c4 & 1) * 4 + t] = h;
        ul.e[(c4 & 1) * 4 + t] = (_Float16)(sc - (float)h);
        const int j = k & 7;
        float sqv = __fmul_rn(e[t], e[t]);
        if ((k & 127) < 8) rj[j] = sqv;
        else rj[j] = __fadd_rn(rj[j], sqv);
      }
      if (c4 & 1) {
        const int g = kt * 8 + (c4 >> 1);
        const int kstep = g >> 1, lhi = g & 1;
        _Float16* dst = Bp + ((size_t)panel * 16 + kstep) * 2048 + lhi * 256 + nin * 8;
        *(half8*)dst = uh.v;
        *(half8*)(dst + 1024) = ul.v;
      }
    }
    if (kt == 1) s0 = __fadd_rn(__fadd_rn(__fadd_rn(rj[0], rj[1]), __fadd_rn(rj[2], rj[3])),
                                __fadd_rn(__fadd_rn(rj[4], rj[5]), __fadd_rn(rj[6], rj[7])));
    if (kt == 3) s1 = __fadd_rn(__fadd_rn(__fadd_rn(rj[0], rj[1]), __fadd_rn(rj[2], rj[3])),
                                __fadd_rn(__fadd_rn(rj[4], rj[5]), __fadd_rn(rj[6], rj[7])));
  }
  c2[r0 + l] = __fadd_rn(s0, s1);
}

// ---- main: block 256m x 256n, 4 waves 2x2, wave tile 128x128 (Tm=4, Tn=4) ----
__global__ __launch_bounds__(256, 1) void vq_mfma_kernel(
    const _Float16* __restrict__ Vhi, const _Float16* __restrict__ Vlo,
    const _Float16* __restrict__ Bp,
    const float* __restrict__ v2, const float* __restrict__ c2,
    uint64_t* __restrict__ pk)
{
  __shared__ __align__(16) _Float16 smem[16384];  // A kt-tile: [plane(2)][256m x 32k]; 32 KB
  __shared__ uint64_t red2[512];                  // [m(256)][wc(2)] final merge

  const int tid  = threadIdx.x;
  const int lane = tid & 63;
  const int wave = tid >> 6;
  const int wr = wave >> 1, wc = wave & 1;
  const int l31 = lane & 31, lhi = lane >> 5;

  const int bid = blockIdx.x;
  // XCD swizzle: linear dispatch -> xcd = bid&7; each XCD sees 2 panels (1 MB B, L2-resident)
  const int panel = (bid & 7) * 2 + ((bid >> 3) & 1);
  const int mblk  = bid >> 4;
  const int m0 = mblk * 256;
  const int n0 = panel * 256;
  const int p32 = (n0 >> 5) + wc * 4;

  // A staging map: g = tid + 256u -> m = g>>2, kb = g&3, chunk c = kb^(m&3)
  int src[4], dst[4];
#pragma unroll
  for (int u = 0; u < 4; ++u) {
    const int g = tid + 256 * u, m = g >> 2, kb = g & 3;
    src[u] = (m0 + m) * D_DIM + kb * 8;
    dst[u] = m * 32 + (kb ^ (m & 3)) * 8;
  }

  float16v acc[4][4];
#pragma unroll
  for (int mb = 0; mb < 4; ++mb)
#pragma unroll
    for (int nb = 0; nb < 4; ++nb) acc[mb][nb] = (float16v)0.0f;

  half8 sh[4], sl[4];
#pragma unroll
  for (int u = 0; u < 4; ++u) {
    sh[u] = *(const half8*)(Vhi + src[u]);
    sl[u] = *(const half8*)(Vlo + src[u]);
  }

  // B register ping-pong by kstep parity
  half8 bh[2][4], bl[2][4];
#pragma unroll
  for (int nb = 0; nb < 4; ++nb) {
    const _Float16* bp = Bp + ((size_t)(p32 + nb) * 16 + 0) * 2048 + lane * 8;
    bh[0][nb] = *(const half8*)bp;
    bl[0][nb] = *(const half8*)(bp + 1024);
  }

#pragma unroll
  for (int kt = 0; kt < 8; ++kt) {
    if (kt) __syncthreads();            // all waves done reading previous A tile
#pragma unroll
    for (int u = 0; u < 4; ++u) {
      *(half8*)(smem + dst[u])        = sh[u];
      *(half8*)(smem + 8192 + dst[u]) = sl[u];
    }
    __syncthreads();
    if (kt < 7) {                       // reg-prefetch next A tile (drains cheaply at barrier)
#pragma unroll
      for (int u = 0; u < 4; ++u) {
        sh[u] = *(const half8*)(Vhi + src[u] + (kt + 1) * 32);
        sl[u] = *(const half8*)(Vlo + src[u] + (kt + 1) * 32);
      }
    }
#pragma unroll
    for (int ks = 0; ks < 2; ++ks) {
      const int kstep = kt * 2 + ks;
      const int cur = kstep & 1, nxt = cur ^ 1;
      if (kstep < 15) {                 // prefetch B(kstep+1); crosses kt barrier in-flight
#pragma unroll
        for (int nb = 0; nb < 4; ++nb) {
          const _Float16* bp = Bp + ((size_t)(p32 + nb) * 16 + kstep + 1) * 2048 + lane * 8;
          bh[nxt][nb] = *(const half8*)bp;
          bl[nxt][nb] = *(const half8*)(bp + 1024);
        }
      }
      half8 ah[4], al[4];
#pragma unroll
      for (int mb = 0; mb < 4; ++mb) {
        const int m = wr * 128 + mb * 32 + l31;
        const int c = (ks * 2 + lhi) ^ (m & 3);
        ah[mb] = *(const half8*)(smem + m * 32 + c * 8);
        al[mb] = *(const half8*)(smem + 8192 + m * 32 + c * 8);
      }
      // product-major: 16 independent accs per product
#pragma unroll
      for (int nb = 0; nb < 4; ++nb)
#pragma unroll
        for (int mb = 0; mb < 4; ++mb)
          acc[mb][nb] = __builtin_amdgcn_mfma_f32_32x32x16_f16(ah[mb], bh[cur][nb], acc[mb][nb], 0, 0, 0);
#pragma unroll
      for (int nb = 0; nb < 4; ++nb)
#pragma unroll
        for (int mb = 0; mb < 4; ++mb)
          acc[mb][nb] = __builtin_amdgcn_mfma_f32_32x32x16_f16(ah[mb], bl[cur][nb], acc[mb][nb], 0, 0, 0);
#pragma unroll
      for (int nb = 0; nb < 4; ++nb)
#pragma unroll
        for (int mb = 0; mb < 4; ++mb)
          acc[mb][nb] = __builtin_amdgcn_mfma_f32_32x32x16_f16(al[mb], bh[cur][nb], acc[mb][nb], 0, 0, 0);
    }
  }

  // ---- epilogue: diff = (v2 - 2*dot) + c2 (np order), argmin, tie -> lowest n ----
  float c2r[4];
#pragma unroll
  for (int nb = 0; nb < 4; ++nb) c2r[nb] = c2[n0 + wc * 128 + nb * 32 + l31];

  __syncthreads();                      // A-LDS dead; reuse as per-wave transpose buffers
  uint64_t* wbuf = (uint64_t*)smem + wave * 1024;   // 8 KB per wave

#pragma unroll
  for (int mb = 0; mb < 4; ++mb) {
#pragma unroll
    for (int r = 0; r < 16; ++r) {
      const int mrow = wr * 128 + mb * 32 + (r & 3) + 8 * (r >> 2) + 4 * lhi;
      const float v2m = v2[m0 + mrow];
      uint64_t b = ~0ULL;
#pragma unroll
      for (int nb = 0; nb < 4; ++nb) {
        const int n = n0 + wc * 128 + nb * 32 + l31;
        float dot = acc[mb][nb][r] * 0x1p-20f;            // exact pow2 unscale
        float dd  = __fadd_rn(__fsub_rn(v2m, 2.0f * dot), c2r[nb]);
        if (n == 0) dd = INFINITY;                        // exclude code 0
        uint64_t p = ((uint64_t)__float_as_uint(dd) << 32) | (uint32_t)n;
        if (p < b) b = p;                                 // dd>0 -> bits monotonic
      }
      wbuf[r * 64 + lhi * 32 + l31] = b;   // flat row f = 2r+lhi at wbuf[f*32 + l31]
    }
    __syncthreads();
    // transpose-read: 2 lanes per flat row f = lane>>1; each reads 16 candidates
    {
      const int f = lane >> 1, hf = lane & 1;
      const uint64_t* rp = wbuf + f * 32 + hf * 16;
      uint64_t m = rp[0];
#pragma unroll
      for (int i = 1; i < 16; ++i) { uint64_t v = rp[i]; if (v < m) m = v; }
      uint64_t o = __shfl_xor((unsigned long long)m, 1);
      if (o < m) m = o;
      if (hf == 0) {
        const int r_ = f >> 1, lh2 = f & 1;
        const int mrow = wr * 128 + mb * 32 + (r_ & 3) + 8 * (r_ >> 2) + 4 * lh2;
        red2[mrow * 2 + wc] = m;
      }
    }
    __syncthreads();
  }

  uint64_t a0 = red2[tid * 2], a1 = red2[tid * 2 + 1];
  pk[(size_t)panel * M_TOTAL + m0 + tid] = a0 < a1 ? a0 : a1;
}

// ---- gather: one wave per query, no barriers ----
__global__ __launch_bounds__(256) void gather_kernel(
    const float* __restrict__ V, const float* __restrict__ W,
    const uint64_t* __restrict__ pk,
    float* __restrict__ out, float* __restrict__ outIdx,
    float* __restrict__ lossPartial)
{
  const int q = blockIdx.x * 4 + (threadIdx.x >> 6);
  const int l = threadIdx.x & 63;
  uint64_t b = (l < NPART) ? pk[(size_t)l * M_TOTAL + q] : ~0ULL;
#pragma unroll
  for (int off = 32; off; off >>= 1) {
    uint64_t o = __shfl_xor((unsigned long long)b, off);
    if (o < b) b = o;
  }
  float4 vv = *(const float4*)(V + (size_t)q * D_DIM + l * 4);
  const float inv = 0.00390625f;
  bool ne = (vv.x != inv) | (vv.y != inv) | (vv.z != inv) | (vv.w != inv);
  const int idx = __ballot(ne) ? (int)(uint32_t)b : 0;
  float4 o4 = *(const float4*)(W + (size_t)idx * D_DIM + l * 4);
  *(float4*)(out + (size_t)q * D_DIM + l * 4) = o4;
  if (l == 0) outIdx[q] = (float)idx;
  float dx = o4.x - vv.x, dy = o4.y - vv.y, dz = o4.z - vv.z, dw = o4.w - vv.w;
  float s = dx * dx + dy * dy + dz * dz + dw * dw;
#pragma unroll
  for (int off = 32; off; off >>= 1) s += __shfl_xor(s, off);
  if (l == 0) lossPartial[q] = s;
}

__global__ __launch_bounds__(256) void finalize_kernel(
    const float* __restrict__ lossPartial, float* __restrict__ out)
{
  const int t = threadIdx.x;
  __shared__ float red[256];
  float s = 0.0f;
  for (int i = t; i < M_TOTAL; i += 256) s += lossPartial[i];
  red[t] = s;
  __syncthreads();
  for (int st = 128; st > 0; st >>= 1) {
    if (t < st) red[t] += red[t + st];
    __syncthreads();
  }
  if (t == 0) {
    out[0] = (float)((double)red[0] / (double)(M_TOTAL * D_DIM));  // loss
    out[1] = 0.0f;                                                 // used
  }
}

extern "C" void kernel_launch(void* const* d_in, const int* in_sizes, int n_in,
                              void* d_out, int out_size, void* d_ws, size_t ws_size,
                              hipStream_t stream) {
  const float* V = (const float*)d_in[0];   // 16384 x 256
  const float* W = (const float*)d_in[1];   // 4096 x 256
  float* out = (float*)d_out;

  // V planes live in d_out (16384*256*4 bytes); gather overwrites later.
  _Float16* Vhi = (_Float16*)d_out;
  _Float16* Vlo = Vhi + VPLANE;

  char* ws = (char*)d_ws;
  _Float16* Bp  = (_Float16*)(ws);                        // packed W frags: 8 MB
  float*    c2  = (float*)(ws + 8388608);                 // 16 KB
  float*    v2  = (float*)(ws + 8388608 + 16384);         // 64 KB
  uint64_t* pk  = (uint64_t*)(ws + 8388608 + 16384 + 65536);   // 16*16384*8 = 2 MB
  float* lossPartial = (float*)(ws + 8388608 + 16384 + 65536 + 2097152);  // 64 KB

  prep_w_kernel<<<NCODES / 64, 64, 0, stream>>>(W, Bp, c2);
  prep_v_kernel<<<M_TOTAL / 64, 64, 0, stream>>>(V, Vhi, Vlo, v2);
  vq_mfma_kernel<<<1024, 256, 0, stream>>>(Vhi, Vlo, Bp, v2, c2, pk);
  gather_kernel<<<M_TOTAL / 4, 256, 0, stream>>>(V, W, pk, out, out + OUT_OFF_IDX, lossPartial);
  finalize_kernel<<<1, 256, 0, stream>>>(lossPartial, out + OUT_OFF_LOSS);
}

// Round 8
// 212.750 us; speedup vs baseline: 1.4931x; 1.0502x over previous
//
#include <hip/hip_runtime.h>
#include <hip/hip_fp16.h>
#include <math.h>
#include <stdint.h>

// VQ via f16x3 split MFMA (32x32x16): dot = (hi.hi + hi.lo + lo.hi) * 2^-20.
// diff = (v2 - 2*dot) + c2 fp32-rounded per np; argmin codes 1..4095, ties -> lowest n.
// R8: Tm=4 x Tn=2 wave tile at 2 waves/SIMD (TLP restored), grid 2048, padded epilogue,
// 256-thread fused prep kernels with shuffle-tree rowsq.

#define M_TOTAL 16384
#define NCODES  4096
#define D_DIM   256

#define OUT_OFF_IDX  (M_TOTAL * D_DIM)
#define OUT_OFF_LOSS (OUT_OFF_IDX + M_TOTAL)

#define NPART 32
#define VPLANE (M_TOTAL * D_DIM)

typedef _Float16 half8 __attribute__((ext_vector_type(8)));
typedef float    float16v __attribute__((ext_vector_type(16)));

// ---- prep V: 16 rows/block, fused split + shuffle-tree rowsq (np pairwise order) ----
__global__ __launch_bounds__(256) void prep_v_kernel(
    const float* __restrict__ X, _Float16* __restrict__ hi, _Float16* __restrict__ lo,
    float* __restrict__ sq)
{
  __shared__ float T[16 * 264];
  const int t = threadIdx.x;
  const int rloc = t >> 4, seg = t & 15;
  const int row = blockIdx.x * 16 + rloc;
  const float* src = X + (size_t)row * D_DIM + seg * 16;
  float4 x[4];
#pragma unroll
  for (int u = 0; u < 4; ++u) x[u] = ((const float4*)src)[u];
  union { half8 v; _Float16 e[8]; } uh[2], ul[2];
#pragma unroll
  for (int u = 0; u < 4; ++u) {
    float e4[4] = {x[u].x, x[u].y, x[u].z, x[u].w};
#pragma unroll
    for (int j = 0; j < 4; ++j) {
      const int e = u * 4 + j;
      float s = e4[j] * 1024.0f;            // exact pow2 scale
      _Float16 h = (_Float16)s;             // RN
      uh[e >> 3].e[e & 7] = h;
      ul[e >> 3].e[e & 7] = (_Float16)(s - (float)h);
    }
    *(float4*)&T[rloc * 264 + seg * 16 + u * 4] = x[u];
  }
  _Float16* hd = hi + (size_t)row * D_DIM + seg * 16;
  _Float16* ld = lo + (size_t)row * D_DIM + seg * 16;
  *(half8*)hd = uh[0].v; *(half8*)(hd + 8) = uh[1].v;
  *(half8*)ld = ul[0].v; *(half8*)(ld + 8) = ul[1].v;
  __syncthreads();
  const int half = (t >> 3) & 1, j = t & 7;
  const float* tr = &T[rloc * 264 + half * 128 + j];
  float r = __fmul_rn(tr[0], tr[0]);
#pragma unroll
  for (int i = 1; i < 16; ++i) { float e = tr[8 * i]; r = __fadd_rn(r, __fmul_rn(e, e)); }
  r = __fadd_rn(r, __shfl_xor(r, 1));   // np: (r0+r1)... fadd commutative -> exact
  r = __fadd_rn(r, __shfl_xor(r, 2));
  r = __fadd_rn(r, __shfl_xor(r, 4));
  r = __fadd_rn(r, __shfl_xor(r, 8));   // pw(0:128) + pw(128:256)
  if ((t & 15) == 0) sq[row] = r;
}

// ---- prep W: 16 rows/block, split + pack to fragment order + rowsq ----
// Bp element (n,k,plane): panel=n>>5, kstep=k>>4, lhi=(k>>3)&1
// offset = (panel*16+kstep)*2048 + plane*1024 + lhi*256 + (n&31)*8 + (k&7)
__global__ __launch_bounds__(256) void prep_w_kernel(
    const float* __restrict__ W, _Float16* __restrict__ Bp, float* __restrict__ c2)
{
  __shared__ float T[16 * 264];
  const int t = threadIdx.x;
  const int rloc = t >> 4, seg = t & 15;   // seg == kstep for this thread's 16 cols
  const int row = blockIdx.x * 16 + rloc;
  const float* src = W + (size_t)row * D_DIM + seg * 16;
  float4 x[4];
#pragma unroll
  for (int u = 0; u < 4; ++u) x[u] = ((const float4*)src)[u];
  union { half8 v; _Float16 e[8]; } uh[2], ul[2];
#pragma unroll
  for (int u = 0; u < 4; ++u) {
    float e4[4] = {x[u].x, x[u].y, x[u].z, x[u].w};
#pragma unroll
    for (int j = 0; j < 4; ++j) {
      const int e = u * 4 + j;
      float s = e4[j] * 1024.0f;
      _Float16 h = (_Float16)s;
      uh[e >> 3].e[e & 7] = h;
      ul[e >> 3].e[e & 7] = (_Float16)(s - (float)h);
    }
    *(float4*)&T[rloc * 264 + seg * 16 + u * 4] = x[u];
  }
  const int panel = row >> 5, nin = row & 31;
  _Float16* dst = Bp + ((size_t)panel * 16 + seg) * 2048 + nin * 8;
#pragma unroll
  for (int lh = 0; lh < 2; ++lh) {
    *(half8*)(dst + lh * 256)        = uh[lh].v;   // hi plane
    *(half8*)(dst + 1024 + lh * 256) = ul[lh].v;   // lo plane
  }
  __syncthreads();
  const int half = (t >> 3) & 1, j = t & 7;
  const float* tr = &T[rloc * 264 + half * 128 + j];
  float r = __fmul_rn(tr[0], tr[0]);
#pragma unroll
  for (int i = 1; i < 16; ++i) { float e = tr[8 * i]; r = __fadd_rn(r, __fmul_rn(e, e)); }
  r = __fadd_rn(r, __shfl_xor(r, 1));
  r = __fadd_rn(r, __shfl_xor(r, 2));
  r = __fadd_rn(r, __shfl_xor(r, 4));
  r = __fadd_rn(r, __shfl_xor(r, 8));
  if ((t & 15) == 0) c2[row] = r;
}

// ---- main: block 256m x 128n, 4 waves 2x2, wave tile 128m x 64n (Tm=4, Tn=2) ----
__global__ __launch_bounds__(256, 2) void vq_mfma_kernel(
    const _Float16* __restrict__ Vhi, const _Float16* __restrict__ Vlo,
    const _Float16* __restrict__ Bp,
    const float* __restrict__ v2, const float* __restrict__ c2,
    uint64_t* __restrict__ pk)
{
  // 0..32768: A tile [plane(2)][256m x 32k]; epilogue: wbuf 4x1056 u64 (33792 B) + red2
  __shared__ __align__(16) char smem_raw[37888];
  _Float16* As = (_Float16*)smem_raw;
  uint64_t* red2 = (uint64_t*)(smem_raw + 33792);  // 512 u64

  const int tid  = threadIdx.x;
  const int lane = tid & 63;
  const int wave = tid >> 6;
  const int wr = wave >> 1, wc = wave & 1;
  const int l31 = lane & 31, lhi = lane >> 5;

  const int bid = blockIdx.x;
  // XCD swizzle: xcd = bid&7 gets panels {4x..4x+3} (1 MB B, L2-resident)
  const int panel = (bid & 7) * 4 + ((bid >> 3) & 3);
  const int mblk  = bid >> 5;
  const int m0 = mblk * 256;
  const int n0 = panel * 128;
  const int p32 = panel * 4 + wc * 2;

  // A staging map: g = tid + 256u -> m = g>>2, kb = g&3, chunk c = kb^(m&3)
  int src[4], dst[4];
#pragma unroll
  for (int u = 0; u < 4; ++u) {
    const int g = tid + 256 * u, m = g >> 2, kb = g & 3;
    src[u] = (m0 + m) * D_DIM + kb * 8;
    dst[u] = m * 32 + (kb ^ (m & 3)) * 8;
  }

  float16v acc[4][2];
#pragma unroll
  for (int mb = 0; mb < 4; ++mb)
#pragma unroll
    for (int nb = 0; nb < 2; ++nb) acc[mb][nb] = (float16v)0.0f;

  half8 sh[4], sl[4];
#pragma unroll
  for (int u = 0; u < 4; ++u) {
    sh[u] = *(const half8*)(Vhi + src[u]);
    sl[u] = *(const half8*)(Vlo + src[u]);
  }

  half8 bh[2][2], bl[2][2];     // B ping-pong by kstep parity
#pragma unroll
  for (int nb = 0; nb < 2; ++nb) {
    const _Float16* bp = Bp + ((size_t)(p32 + nb) * 16) * 2048 + lane * 8;
    bh[0][nb] = *(const half8*)bp;
    bl[0][nb] = *(const half8*)(bp + 1024);
  }

  for (int kt = 0; kt < 8; ++kt) {
    if (kt) __syncthreads();
#pragma unroll
    for (int u = 0; u < 4; ++u) {
      *(half8*)(As + dst[u])        = sh[u];
      *(half8*)(As + 8192 + dst[u]) = sl[u];
    }
    __syncthreads();
    if (kt < 7) {
#pragma unroll
      for (int u = 0; u < 4; ++u) {
        sh[u] = *(const half8*)(Vhi + src[u] + (kt + 1) * 32);
        sl[u] = *(const half8*)(Vlo + src[u] + (kt + 1) * 32);
      }
    }
#pragma unroll
    for (int ks = 0; ks < 2; ++ks) {
      const int kstep = kt * 2 + ks;
      const int cur = kstep & 1, nxt = cur ^ 1;
      if (kstep < 15) {
#pragma unroll
        for (int nb = 0; nb < 2; ++nb) {
          const _Float16* bp = Bp + ((size_t)(p32 + nb) * 16 + kstep + 1) * 2048 + lane * 8;
          bh[nxt][nb] = *(const half8*)bp;
          bl[nxt][nb] = *(const half8*)(bp + 1024);
        }
      }
      half8 ah[4], al[4];
#pragma unroll
      for (int mb = 0; mb < 4; ++mb) {
        const int m = wr * 128 + mb * 32 + l31;
        const int c = (ks * 2 + lhi) ^ (m & 3);
        ah[mb] = *(const half8*)(As + m * 32 + c * 8);
        al[mb] = *(const half8*)(As + 8192 + m * 32 + c * 8);
      }
      // product-major: 8 independent accs per product
#pragma unroll
      for (int nb = 0; nb < 2; ++nb)
#pragma unroll
        for (int mb = 0; mb < 4; ++mb)
          acc[mb][nb] = __builtin_amdgcn_mfma_f32_32x32x16_f16(ah[mb], bh[cur][nb], acc[mb][nb], 0, 0, 0);
#pragma unroll
      for (int nb = 0; nb < 2; ++nb)
#pragma unroll
        for (int mb = 0; mb < 4; ++mb)
          acc[mb][nb] = __builtin_amdgcn_mfma_f32_32x32x16_f16(ah[mb], bl[cur][nb], acc[mb][nb], 0, 0, 0);
#pragma unroll
      for (int nb = 0; nb < 2; ++nb)
#pragma unroll
        for (int mb = 0; mb < 4; ++mb)
          acc[mb][nb] = __builtin_amdgcn_mfma_f32_32x32x16_f16(al[mb], bh[cur][nb], acc[mb][nb], 0, 0, 0);
    }
  }

  // ---- epilogue: diff = (v2 - 2*dot) + c2 (np order), argmin, tie -> lowest n ----
  float c2r[2];
#pragma unroll
  for (int nb = 0; nb < 2; ++nb) c2r[nb] = c2[n0 + wc * 64 + nb * 32 + l31];

  __syncthreads();                      // A-LDS dead; per-wave padded transpose buffers
  uint64_t* wbuf = (uint64_t*)smem_raw + wave * 1056;   // 32 rows x 33 u64

#pragma unroll
  for (int mb = 0; mb < 4; ++mb) {
#pragma unroll
    for (int r = 0; r < 16; ++r) {
      const int rowin = (r & 3) + 8 * (r >> 2) + 4 * lhi;
      const float v2m = v2[m0 + wr * 128 + mb * 32 + rowin];
      uint64_t b = ~0ULL;
#pragma unroll
      for (int nb = 0; nb < 2; ++nb) {
        const int n = n0 + wc * 64 + nb * 32 + l31;
        float dot = acc[mb][nb][r] * 0x1p-20f;            // exact pow2 unscale
        float dd  = __fadd_rn(__fsub_rn(v2m, 2.0f * dot), c2r[nb]);
        if (n == 0) dd = INFINITY;                        // exclude code 0
        uint64_t p = ((uint64_t)__float_as_uint(dd) << 32) | (uint32_t)n;
        if (p < b) b = p;                                 // dd>0 -> bits monotonic
      }
      wbuf[(r * 2 + lhi) * 33 + l31] = b;                 // padded: banks spread
    }
    __syncthreads();
    {
      const int f = lane >> 1, hf = lane & 1;
      const uint64_t* rp = wbuf + f * 33 + hf * 16;
      uint64_t m = rp[0];
#pragma unroll
      for (int i = 1; i < 16; ++i) { uint64_t v = rp[i]; if (v < m) m = v; }
      uint64_t o = __shfl_xor((unsigned long long)m, 1);
      if (o < m) m = o;
      if (hf == 0) {
        const int r_ = f >> 1, lh2 = f & 1;
        const int rowin = (r_ & 3) + 8 * (r_ >> 2) + 4 * lh2;
        red2[(wr * 128 + mb * 32 + rowin) * 2 + wc] = m;
      }
    }
    __syncthreads();
  }

  uint64_t a0 = red2[tid * 2], a1 = red2[tid * 2 + 1];
  pk[(size_t)panel * M_TOTAL + m0 + tid] = a0 < a1 ? a0 : a1;
}

// ---- gather: one wave per query, no barriers ----
__global__ __launch_bounds__(256) void gather_kernel(
    const float* __restrict__ V, const float* __restrict__ W,
    const uint64_t* __restrict__ pk,
    float* __restrict__ out, float* __restrict__ outIdx,
    float* __restrict__ lossPartial)
{
  const int q = blockIdx.x * 4 + (threadIdx.x >> 6);
  const int l = threadIdx.x & 63;
  uint64_t b = (l < NPART) ? pk[(size_t)l * M_TOTAL + q] : ~0ULL;
#pragma unroll
  for (int off = 32; off; off >>= 1) {
    uint64_t o = __shfl_xor((unsigned long long)b, off);
    if (o < b) b = o;
  }
  float4 vv = *(const float4*)(V + (size_t)q * D_DIM + l * 4);
  const float inv = 0.00390625f;
  bool ne = (vv.x != inv) | (vv.y != inv) | (vv.z != inv) | (vv.w != inv);
  const int idx = __ballot(ne) ? (int)(uint32_t)b : 0;
  float4 o4 = *(const float4*)(W + (size_t)idx * D_DIM + l * 4);
  *(float4*)(out + (size_t)q * D_DIM + l * 4) = o4;
  if (l == 0) outIdx[q] = (float)idx;
  float dx = o4.x - vv.x, dy = o4.y - vv.y, dz = o4.z - vv.z, dw = o4.w - vv.w;
  float s = dx * dx + dy * dy + dz * dz + dw * dw;
#pragma unroll
  for (int off = 32; off; off >>= 1) s += __shfl_xor(s, off);
  if (l == 0) lossPartial[q] = s;
}

__global__ __launch_bounds__(256) void finalize_kernel(
    const float* __restrict__ lossPartial, float* __restrict__ out)
{
  const int t = threadIdx.x;
  __shared__ float red[256];
  float s = 0.0f;
  for (int i = t; i < M_TOTAL; i += 256) s += lossPartial[i];
  red[t] = s;
  __syncthreads();
  for (int st = 128; st > 0; st >>= 1) {
    if (t < st) red[t] += red[t + st];
    __syncthreads();
  }
  if (t == 0) {
    out[0] = (float)((double)red[0] / (double)(M_TOTAL * D_DIM));  // loss
    out[1] = 0.0f;                                                 // used
  }
}

extern "C" void kernel_launch(void* const* d_in, const int* in_sizes, int n_in,
                              void* d_out, int out_size, void* d_ws, size_t ws_size,
                              hipStream_t stream) {
  const float* V = (const float*)d_in[0];   // 16384 x 256
  const float* W = (const float*)d_in[1];   // 4096 x 256
  float* out = (float*)d_out;

  // V planes live in d_out (16384*256*4 bytes); gather overwrites later.
  _Float16* Vhi = (_Float16*)d_out;
  _Float16* Vlo = Vhi + VPLANE;

  char* ws = (char*)d_ws;
  _Float16* Bp  = (_Float16*)(ws);                        // packed W frags: 8 MB
  float*    c2  = (float*)(ws + 8388608);                 // 16 KB
  float*    v2  = (float*)(ws + 8388608 + 16384);         // 64 KB
  uint64_t* pk  = (uint64_t*)(ws + 8388608 + 16384 + 65536);   // 32*16384*8 = 4 MB
  float* lossPartial = (float*)(ws + 8388608 + 16384 + 65536 + 4194304);  // 64 KB

  prep_w_kernel<<<NCODES / 16, 256, 0, stream>>>(W, Bp, c2);
  prep_v_kernel<<<M_TOTAL / 16, 256, 0, stream>>>(V, Vhi, Vlo, v2);
  vq_mfma_kernel<<<2048, 256, 0, stream>>>(Vhi, Vlo, Bp, v2, c2, pk);
  gather_kernel<<<M_TOTAL / 4, 256, 0, stream>>>(V, W, pk, out, out + OUT_OFF_IDX, lossPartial);
  finalize_kernel<<<1, 256, 0, stream>>>(lossPartial, out + OUT_OFF_LOSS);
}

// Round 9
// 204.342 us; speedup vs baseline: 1.5545x; 1.0411x over previous
//
#include <hip/hip_runtime.h>
#include <hip/hip_fp16.h>
#include <math.h>
#include <stdint.h>

// VQ via f16x3 split MFMA (32x32x16): dot = (hi.hi + hi.lo + lo.hi) * 2^-20.
// diff = (v2 - 2*dot) + c2 fp32-rounded per np; argmin codes 1..4095, ties -> lowest n.
// R9: double-buffered A-LDS (1 barrier/kt), global u64 atomicMin argmin (pk[16384]),
// fused prep launch, simplified gather.

#define M_TOTAL 16384
#define NCODES  4096
#define D_DIM   256

#define OUT_OFF_IDX  (M_TOTAL * D_DIM)
#define OUT_OFF_LOSS (OUT_OFF_IDX + M_TOTAL)

#define VPLANE (M_TOTAL * D_DIM)

typedef _Float16 half8 __attribute__((ext_vector_type(8)));
typedef float    float16v __attribute__((ext_vector_type(16)));

// ---- fused prep: blocks 0..255 = W (split+pack+c2), 256..1279 = V (split+v2+pk init) ----
// Bp element (n,k,plane): panel=n>>5, kstep=k>>4, lhi=(k>>3)&1
// offset = (panel*16+kstep)*2048 + plane*1024 + lhi*256 + (n&31)*8 + (k&7)
__global__ __launch_bounds__(256) void prep_kernel(
    const float* __restrict__ V, const float* __restrict__ W,
    _Float16* __restrict__ Vhi, _Float16* __restrict__ Vlo,
    _Float16* __restrict__ Bp, float* __restrict__ v2, float* __restrict__ c2,
    uint64_t* __restrict__ pk)
{
  __shared__ float T[16 * 264];
  const int t = threadIdx.x;
  const int rloc = t >> 4, seg = t & 15;
  const bool isW = blockIdx.x < 256;
  const int bid2 = isW ? blockIdx.x : (blockIdx.x - 256);
  const int row = bid2 * 16 + rloc;
  const float* X = isW ? W : V;

  if (!isW && bid2 < 64) pk[bid2 * 256 + t] = ~0ULL;   // init argmin array

  const float* src = X + (size_t)row * D_DIM + seg * 16;
  float4 x[4];
#pragma unroll
  for (int u = 0; u < 4; ++u) x[u] = ((const float4*)src)[u];
  union { half8 v; _Float16 e[8]; } uh[2], ul[2];
#pragma unroll
  for (int u = 0; u < 4; ++u) {
    float e4[4] = {x[u].x, x[u].y, x[u].z, x[u].w};
#pragma unroll
    for (int j = 0; j < 4; ++j) {
      const int e = u * 4 + j;
      float s = e4[j] * 1024.0f;            // exact pow2 scale
      _Float16 h = (_Float16)s;             // RN
      uh[e >> 3].e[e & 7] = h;
      ul[e >> 3].e[e & 7] = (_Float16)(s - (float)h);  // RN of exact residual
    }
    *(float4*)&T[rloc * 264 + seg * 16 + u * 4] = x[u];
  }
  if (isW) {
    const int panel = row >> 5, nin = row & 31;
    _Float16* dst = Bp + ((size_t)panel * 16 + seg) * 2048 + nin * 8;
#pragma unroll
    for (int lh = 0; lh < 2; ++lh) {
      *(half8*)(dst + lh * 256)        = uh[lh].v;   // hi plane
      *(half8*)(dst + 1024 + lh * 256) = ul[lh].v;   // lo plane
    }
  } else {
    _Float16* hd = Vhi + (size_t)row * D_DIM + seg * 16;
    _Float16* ld = Vlo + (size_t)row * D_DIM + seg * 16;
    *(half8*)hd = uh[0].v; *(half8*)(hd + 8) = uh[1].v;
    *(half8*)ld = ul[0].v; *(half8*)(ld + 8) = ul[1].v;
  }
  __syncthreads();
  // rowsq, numpy pairwise chain order (fadd commutative -> shuffle tree exact)
  const int half = (t >> 3) & 1, j = t & 7;
  const float* tr = &T[rloc * 264 + half * 128 + j];
  float r = __fmul_rn(tr[0], tr[0]);
#pragma unroll
  for (int i = 1; i < 16; ++i) { float e = tr[8 * i]; r = __fadd_rn(r, __fmul_rn(e, e)); }
  r = __fadd_rn(r, __shfl_xor(r, 1));
  r = __fadd_rn(r, __shfl_xor(r, 2));
  r = __fadd_rn(r, __shfl_xor(r, 4));
  r = __fadd_rn(r, __shfl_xor(r, 8));   // pw(0:128) + pw(128:256)
  if ((t & 15) == 0) { if (isW) c2[row] = r; else v2[row] = r; }
}

// ---- main: block 256m x 128n, 4 waves 2x2, wave tile 128m x 64n (Tm=4, Tn=2) ----
// Double-buffered A-LDS: one barrier per kt; argmin merged globally via u64 atomicMin.
__global__ __launch_bounds__(256, 2) void vq_mfma_kernel(
    const _Float16* __restrict__ Vhi, const _Float16* __restrict__ Vlo,
    const _Float16* __restrict__ Bp,
    const float* __restrict__ v2, const float* __restrict__ c2,
    uint64_t* __restrict__ pk)
{
  // [0,65536): A dbuf [buf(2)][plane(2)][256m x 32k]; epilogue reuses as wbuf
  // [65536,69632): red2[512]
  __shared__ __align__(16) char smem_raw[69632];
  _Float16* As = (_Float16*)smem_raw;
  uint64_t* red2 = (uint64_t*)(smem_raw + 65536);

  const int tid  = threadIdx.x;
  const int lane = tid & 63;
  const int wave = tid >> 6;
  const int wr = wave >> 1, wc = wave & 1;
  const int l31 = lane & 31, lhi = lane >> 5;

  const int bid = blockIdx.x;
  // XCD swizzle: xcd = bid&7 gets panels {4x..4x+3} (512 KB B, L2-resident)
  const int panel = (bid & 7) * 4 + ((bid >> 3) & 3);
  const int mblk  = bid >> 5;
  const int m0 = mblk * 256;
  const int n0 = panel * 128;
  const int p32 = panel * 4 + wc * 2;

  // A staging map: g = tid + 256u -> m = g>>2, kb = g&3, chunk c = kb^(m&3)
  int src[4], dst[4];
#pragma unroll
  for (int u = 0; u < 4; ++u) {
    const int g = tid + 256 * u, m = g >> 2, kb = g & 3;
    src[u] = (m0 + m) * D_DIM + kb * 8;
    dst[u] = m * 32 + (kb ^ (m & 3)) * 8;
  }

  float16v acc[4][2];
#pragma unroll
  for (int mb = 0; mb < 4; ++mb)
#pragma unroll
    for (int nb = 0; nb < 2; ++nb) acc[mb][nb] = (float16v)0.0f;

  half8 sh[4], sl[4];
#pragma unroll
  for (int u = 0; u < 4; ++u) {
    sh[u] = *(const half8*)(Vhi + src[u]);
    sl[u] = *(const half8*)(Vlo + src[u]);
  }
#pragma unroll
  for (int u = 0; u < 4; ++u) {         // stage kt0 into buf0
    *(half8*)(As + dst[u])        = sh[u];
    *(half8*)(As + 8192 + dst[u]) = sl[u];
  }

  half8 bh[2][2], bl[2][2];             // B ping-pong by kstep parity
#pragma unroll
  for (int nb = 0; nb < 2; ++nb) {
    const _Float16* bp = Bp + ((size_t)(p32 + nb) * 16) * 2048 + lane * 8;
    bh[0][nb] = *(const half8*)bp;
    bl[0][nb] = *(const half8*)(bp + 1024);
  }
  __syncthreads();                      // buf0 visible

  for (int kt = 0; kt < 8; ++kt) {
    const int cur = kt & 1;
    _Float16* Ac = As + cur * 16384;
    if (kt < 7) {                       // global -> regs for next tile
#pragma unroll
      for (int u = 0; u < 4; ++u) {
        sh[u] = *(const half8*)(Vhi + src[u] + (kt + 1) * 32);
        sl[u] = *(const half8*)(Vlo + src[u] + (kt + 1) * 32);
      }
    }
#pragma unroll
    for (int ks = 0; ks < 2; ++ks) {
      const int kstep = kt * 2 + ks;
      const int pcur = kstep & 1, pnxt = pcur ^ 1;
      if (kstep < 15) {                 // B prefetch overlaps MFMAs
#pragma unroll
        for (int nb = 0; nb < 2; ++nb) {
          const _Float16* bp = Bp + ((size_t)(p32 + nb) * 16 + kstep + 1) * 2048 + lane * 8;
          bh[pnxt][nb] = *(const half8*)bp;
          bl[pnxt][nb] = *(const half8*)(bp + 1024);
        }
      }
      half8 ah[4], al[4];
#pragma unroll
      for (int mb = 0; mb < 4; ++mb) {
        const int m = wr * 128 + mb * 32 + l31;
        const int c = (ks * 2 + lhi) ^ (m & 3);
        ah[mb] = *(const half8*)(Ac + m * 32 + c * 8);
        al[mb] = *(const half8*)(Ac + 8192 + m * 32 + c * 8);
      }
      // product-major: 8 independent accs per product
#pragma unroll
      for (int nb = 0; nb < 2; ++nb)
#pragma unroll
        for (int mb = 0; mb < 4; ++mb)
          acc[mb][nb] = __builtin_amdgcn_mfma_f32_32x32x16_f16(ah[mb], bh[pcur][nb], acc[mb][nb], 0, 0, 0);
#pragma unroll
      for (int nb = 0; nb < 2; ++nb)
#pragma unroll
        for (int mb = 0; mb < 4; ++mb)
          acc[mb][nb] = __builtin_amdgcn_mfma_f32_32x32x16_f16(ah[mb], bl[pcur][nb], acc[mb][nb], 0, 0, 0);
#pragma unroll
      for (int nb = 0; nb < 2; ++nb)
#pragma unroll
        for (int mb = 0; mb < 4; ++mb)
          acc[mb][nb] = __builtin_amdgcn_mfma_f32_32x32x16_f16(al[mb], bh[pcur][nb], acc[mb][nb], 0, 0, 0);
    }
    if (kt < 7) {                       // write next tile into other buffer (post-MFMA: vmcnt cheap)
      _Float16* An = As + (cur ^ 1) * 16384;
#pragma unroll
      for (int u = 0; u < 4; ++u) {
        *(half8*)(An + dst[u])        = sh[u];
        *(half8*)(An + 8192 + dst[u]) = sl[u];
      }
    }
    __syncthreads();                    // one barrier per kt
  }

  // ---- epilogue: diff = (v2 - 2*dot) + c2 (np order), argmin, tie -> lowest n ----
  float c2r[2];
#pragma unroll
  for (int nb = 0; nb < 2; ++nb) c2r[nb] = c2[n0 + wc * 64 + nb * 32 + l31];

  uint64_t* wbuf = (uint64_t*)smem_raw + wave * 1056;   // 32 rows x 33 u64, per wave

#pragma unroll
  for (int mb = 0; mb < 4; ++mb) {
#pragma unroll
    for (int r = 0; r < 16; ++r) {
      const int rowin = (r & 3) + 8 * (r >> 2) + 4 * lhi;
      const float v2m = v2[m0 + wr * 128 + mb * 32 + rowin];
      uint64_t b = ~0ULL;
#pragma unroll
      for (int nb = 0; nb < 2; ++nb) {
        const int n = n0 + wc * 64 + nb * 32 + l31;
        float dot = acc[mb][nb][r] * 0x1p-20f;            // exact pow2 unscale
        float dd  = __fadd_rn(__fsub_rn(v2m, 2.0f * dot), c2r[nb]);
        if (n == 0) dd = INFINITY;                        // exclude code 0
        uint64_t p = ((uint64_t)__float_as_uint(dd) << 32) | (uint32_t)n;
        if (p < b) b = p;                                 // dd>0 -> bits monotonic
      }
      wbuf[(r * 2 + lhi) * 33 + l31] = b;
    }
    __syncthreads();
    {
      const int f = lane >> 1, hf = lane & 1;
      const uint64_t* rp = wbuf + f * 33 + hf * 16;
      uint64_t m = rp[0];
#pragma unroll
      for (int i = 1; i < 16; ++i) { uint64_t v = rp[i]; if (v < m) m = v; }
      uint64_t o = __shfl_xor((unsigned long long)m, 1);
      if (o < m) m = o;
      if (hf == 0) {
        const int r_ = f >> 1, lh2 = f & 1;
        const int rowin = (r_ & 3) + 8 * (r_ >> 2) + 4 * lh2;
        red2[(wr * 128 + mb * 32 + rowin) * 2 + wc] = m;
      }
    }
    __syncthreads();
  }

  uint64_t a0 = red2[tid * 2], a1 = red2[tid * 2 + 1];
  atomicMin((unsigned long long*)&pk[m0 + tid], (unsigned long long)(a0 < a1 ? a0 : a1));
}

// ---- gather: one wave per query, no barriers ----
__global__ __launch_bounds__(256) void gather_kernel(
    const float* __restrict__ V, const float* __restrict__ W,
    const uint64_t* __restrict__ pk,
    float* __restrict__ out, float* __restrict__ outIdx,
    float* __restrict__ lossPartial)
{
  const int q = blockIdx.x * 4 + (threadIdx.x >> 6);
  const int l = threadIdx.x & 63;
  const uint64_t b = pk[q];             // wave-uniform broadcast load
  float4 vv = *(const float4*)(V + (size_t)q * D_DIM + l * 4);
  const float inv = 0.00390625f;
  bool ne = (vv.x != inv) | (vv.y != inv) | (vv.z != inv) | (vv.w != inv);
  const int idx = __ballot(ne) ? (int)(uint32_t)b : 0;
  float4 o4 = *(const float4*)(W + (size_t)idx * D_DIM + l * 4);
  *(float4*)(out + (size_t)q * D_DIM + l * 4) = o4;
  if (l == 0) outIdx[q] = (float)idx;
  float dx = o4.x - vv.x, dy = o4.y - vv.y, dz = o4.z - vv.z, dw = o4.w - vv.w;
  float s = dx * dx + dy * dy + dz * dz + dw * dw;
#pragma unroll
  for (int off = 32; off; off >>= 1) s += __shfl_xor(s, off);
  if (l == 0) lossPartial[q] = s;
}

__global__ __launch_bounds__(256) void finalize_kernel(
    const float* __restrict__ lossPartial, float* __restrict__ out)
{
  const int t = threadIdx.x;
  __shared__ float red[256];
  float s = 0.0f;
  for (int i = t; i < M_TOTAL; i += 256) s += lossPartial[i];
  red[t] = s;
  __syncthreads();
  for (int st = 128; st > 0; st >>= 1) {
    if (t < st) red[t] += red[t + st];
    __syncthreads();
  }
  if (t == 0) {
    out[0] = (float)((double)red[0] / (double)(M_TOTAL * D_DIM));  // loss
    out[1] = 0.0f;                                                 // used
  }
}

extern "C" void kernel_launch(void* const* d_in, const int* in_sizes, int n_in,
                              void* d_out, int out_size, void* d_ws, size_t ws_size,
                              hipStream_t stream) {
  const float* V = (const float*)d_in[0];   // 16384 x 256
  const float* W = (const float*)d_in[1];   // 4096 x 256
  float* out = (float*)d_out;

  // V planes live in d_out (16384*256*4 bytes); gather overwrites later.
  _Float16* Vhi = (_Float16*)d_out;
  _Float16* Vlo = Vhi + VPLANE;

  char* ws = (char*)d_ws;
  _Float16* Bp  = (_Float16*)(ws);                        // packed W frags: 4 MB used
  float*    c2  = (float*)(ws + 8388608);                 // 16 KB
  float*    v2  = (float*)(ws + 8388608 + 16384);         // 64 KB
  uint64_t* pk  = (uint64_t*)(ws + 8388608 + 16384 + 65536);   // 16384 u64 = 128 KB
  float* lossPartial = (float*)(ws + 8388608 + 16384 + 65536 + 131072);  // 64 KB

  prep_kernel<<<1280, 256, 0, stream>>>(V, W, Vhi, Vlo, Bp, v2, c2, pk);
  vq_mfma_kernel<<<2048, 256, 0, stream>>>(Vhi, Vlo, Bp, v2, c2, pk);
  gather_kernel<<<M_TOTAL / 4, 256, 0, stream>>>(V, W, pk, out, out + OUT_OFF_IDX, lossPartial);
  finalize_kernel<<<1, 256, 0, stream>>>(lossPartial, out + OUT_OFF_LOSS);
}